// Round 17
// baseline (128.013 us; speedup 1.0000x reference)
//
#include <hip/hip_runtime.h>
#include <hip/hip_cooperative_groups.h>
#include <cstddef>
#include <cstdint>

namespace cg = cooperative_groups;

#define Bq 64
#define Tq 90
#define Oq 5
#define Dq 256
#define Hq 256
#define EAq 4096
#define Rq 5
#define NBq 8
#define NPGq 95
#define KAq 480           // A2 cols: 5 relations x 96

typedef __attribute__((ext_vector_type(8))) short bf16x8;
typedef __attribute__((ext_vector_type(8))) unsigned short u16x8;
typedef __attribute__((ext_vector_type(4))) float f32x4;
typedef __attribute__((address_space(1))) const unsigned int gu32;
typedef __attribute__((address_space(3))) unsigned int lu32;

__device__ __forceinline__ unsigned short f2bf(float f) {
    unsigned u = __float_as_uint(f);
    unsigned r = (u + 0x7FFF + ((u >> 16) & 1)) >> 16;
    return (unsigned short)r;
}
__device__ __forceinline__ float bf2f(unsigned short s) {
    return __uint_as_float(((unsigned)s) << 16);
}

// ---- single cooperative kernel: phase1 {attn | Wt | Xs-prestage} -> grid.sync -> gemm3 ----
__global__ __launch_bounds__(576) void k_all(const float* __restrict__ M,
                                             const float* __restrict__ Ws,
                                             const float* __restrict__ natt,
                                             const int* __restrict__ esrc,
                                             const int* __restrict__ edst,
                                             const int* __restrict__ etype,
                                             const float* __restrict__ x,
                                             const float* __restrict__ bases,
                                             const float* __restrict__ comp,
                                             const float* __restrict__ rootw,
                                             const float* __restrict__ bias,
                                             unsigned short* __restrict__ A2b,
                                             unsigned short* __restrict__ Wt,
                                             float* __restrict__ out) {
    __shared__ __attribute__((aligned(16))) char lds[145408];
    // phase A (attn): Mb@0 48K, Wb@49152 48K; then P@0 [96][97], Acc@49152 [96][96], stats@137216
    unsigned short* Mb = (unsigned short*)lds;
    unsigned short* Wb = (unsigned short*)(lds + 49152);
    float* P   = (float*)lds;
    float* Acc = (float*)(lds + 49152);
    float* mxs = (float*)(lds + 137216);
    float* rds = (float*)(lds + 137600);
    // phase B (gemm3): Xs@0 48K, Wl0@49152 32K, Wl1@81920 32K, Ztl@114688 12K, A2l@126976 18K
    char* const Xs  = lds;
    char* const Wl0 = lds + 49152;
    char* const Wl1 = lds + 81920;
    char* const Ztl = lds + 114688;
    char* const A2l = lds + 126976;

    const int tid = threadIdx.x;
    const int w = tid >> 6, l = tid & 63;
    const int blk = blockIdx.x;
    const int b  = blk & 63;          // graph id for both phases
    const int hc = blk >> 6;          // 0..3 h-chunk (phase B)

    auto stageXs = [&]() {            // convert graph b's x rows fp32->bf16 into swizzled Xs
#pragma unroll
        for (int i = 0; i < 6; ++i) {
            int idx = tid + i * 576;
            if (idx < 3072) {
                int row = idx >> 5, c = idx & 31;
                u16x8 pk;
                if (row < NPGq) {
                    const float4* xs4 = (const float4*)(x + ((size_t)b * NPGq + row) * Dq + c * 8);
                    float4 a = xs4[0], b2 = xs4[1];
                    pk[0] = f2bf(a.x);  pk[1] = f2bf(a.y);  pk[2] = f2bf(a.z);  pk[3] = f2bf(a.w);
                    pk[4] = f2bf(b2.x); pk[5] = f2bf(b2.y); pk[6] = f2bf(b2.z); pk[7] = f2bf(b2.w);
                } else {
#pragma unroll
                    for (int q = 0; q < 8; ++q) pk[q] = 0;
                }
                *(u16x8*)(Xs + row * 512 + ((c * 16) ^ ((row & 7) << 4))) = pk;
            }
        }
    };

    // =============================== PHASE 1 ===============================
    if (blk < 64) {
        // ---- attn for graph b -> A2b (R14-proven LDS-scatter) ----
        int es[8], ed[8], et[8];
#pragma unroll
        for (int k = 0; k < 8; ++k) {
            int j = tid + k * 576;
            if (j < EAq) {
                es[k] = esrc[(size_t)b * EAq + j];
                ed[k] = edst[(size_t)b * EAq + j];
                et[k] = etype[(size_t)b * EAq + j];
            }
        }
        float tagv = (tid < Tq * Oq) ? natt[(size_t)b * (Tq * Oq) + tid] : 0.f;

#pragma unroll
        for (int i = 0; i < 6; ++i) {
            int idx = tid + i * 576;
            if (idx < 3072) {
                int row = idx >> 5, c = idx & 31;
                u16x8 pm, pw;
                if (row < Tq) {
                    const float4* ms = (const float4*)(M + ((size_t)b * Tq + row) * Dq + c * 8);
                    float4 a0 = ms[0], a1 = ms[1];
                    pm[0] = f2bf(a0.x); pm[1] = f2bf(a0.y); pm[2] = f2bf(a0.z); pm[3] = f2bf(a0.w);
                    pm[4] = f2bf(a1.x); pm[5] = f2bf(a1.y); pm[6] = f2bf(a1.z); pm[7] = f2bf(a1.w);
                    const float4* ws = (const float4*)(Ws + (size_t)row * Dq + c * 8);
                    float4 w0 = ws[0], w1 = ws[1];
                    pw[0] = f2bf(w0.x); pw[1] = f2bf(w0.y); pw[2] = f2bf(w0.z); pw[3] = f2bf(w0.w);
                    pw[4] = f2bf(w1.x); pw[5] = f2bf(w1.y); pw[6] = f2bf(w1.z); pw[7] = f2bf(w1.w);
                } else {
#pragma unroll
                    for (int q = 0; q < 8; ++q) { pm[q] = 0; pw[q] = 0; }
                }
                int off = row * 512 + ((c * 16) ^ ((row & 7) << 4));
                *(u16x8*)((char*)Mb + off) = pm;
                *(u16x8*)((char*)Wb + off) = pw;
            }
        }
        __syncthreads();

        {
            const int wr = w / 3, wc = w % 3;
            f32x4 pacc[2][2];
#pragma unroll
            for (int i = 0; i < 2; ++i)
#pragma unroll
                for (int j = 0; j < 2; ++j) pacc[i][j] = (f32x4)0.0f;
#pragma unroll
            for (int ks = 0; ks < 8; ++ks) {
                int kb = ks * 64 + (l >> 4) * 16;
                bf16x8 af[2], bfv[2];
#pragma unroll
                for (int mi = 0; mi < 2; ++mi) {
                    int row = wr * 32 + mi * 16 + (l & 15);
                    af[mi] = *(const bf16x8*)((char*)Mb + row * 512 + (kb ^ ((row & 7) << 4)));
                }
#pragma unroll
                for (int ni = 0; ni < 2; ++ni) {
                    int row = wc * 32 + ni * 16 + (l & 15);
                    bfv[ni] = *(const bf16x8*)((char*)Wb + row * 512 + (kb ^ ((row & 7) << 4)));
                }
#pragma unroll
                for (int mi = 0; mi < 2; ++mi)
#pragma unroll
                    for (int ni = 0; ni < 2; ++ni)
                        pacc[mi][ni] = __builtin_amdgcn_mfma_f32_16x16x32_bf16(
                            af[mi], bfv[ni], pacc[mi][ni], 0, 0, 0);
            }
            __syncthreads();   // MFMA reads done; Mb->P, Wb->Acc reuse legal

#pragma unroll
            for (int mi = 0; mi < 2; ++mi)
#pragma unroll
                for (int ni = 0; ni < 2; ++ni)
#pragma unroll
                    for (int j = 0; j < 4; ++j) {
                        int rowp = wr * 32 + mi * 16 + (l >> 4) * 4 + j;
                        int colp = wc * 32 + ni * 16 + (l & 15);
                        P[rowp * 97 + colp] = pacc[mi][ni][j];
                    }
        }
        __syncthreads();

        if (tid < 96) {
            float m = -1e30f;
            for (int t = 0; t < Tq; ++t) m = fmaxf(m, P[t * 97 + tid]);
            float s = 0.f;
            for (int t = 0; t < Tq; ++t) s += __expf(P[t * 97 + tid] - m);
            mxs[tid] = m;
            rds[tid] = 1.f / s;
        }
        __syncthreads();

        float v[8];
#pragma unroll
        for (int k = 0; k < 8; ++k) {
            int j = tid + k * 576;
            if (j < EAq)
                v[k] = __expf(P[ed[k] * 97 + es[k]] - mxs[es[k]]) * rds[es[k]];
        }

        for (int r = 0; r < Rq; ++r) {
#pragma unroll
            for (int i = 0; i < 4; ++i)                      // zero 9216 floats exact
                ((float4*)Acc)[tid + i * 576] = make_float4(0.f, 0.f, 0.f, 0.f);
            __syncthreads();
#pragma unroll
            for (int k = 0; k < 8; ++k) {
                int j = tid + k * 576;
                if (j < EAq && et[k] == r)
                    atomicAdd(&Acc[ed[k] * 96 + es[k]], v[k]);
            }
            if (r == Rq - 1 && tid < Tq * Oq) {
                int t = tid / Oq, o = tid % Oq;
                Acc[(Tq + o) * 96 + t] = tagv;
            }
            __syncthreads();
#pragma unroll
            for (int i = 0; i < 2; ++i) {
                int c0 = tid + i * 576;                      // 0..1151
                const float* src = Acc + (c0 / 12) * 96 + (c0 % 12) * 8;
                u16x8 pk;
#pragma unroll
                for (int q = 0; q < 8; ++q) pk[q] = f2bf(src[q]);
                *(u16x8*)(A2b + ((size_t)b * 96 + c0 / 12) * KAq + r * 96 + (c0 % 12) * 8) = pk;
            }
            __syncthreads();
        }
    } else if (blk < 112) {
        // ---- Wt compute (48 blocks; 256 active threads) ----
        float* Ld = (float*)lds;          // [32][257]
        int wblk = blk - 64;              // 0..47
        int rs = wblk >> 3;               // 0..5
        int d0 = (wblk & 7) * 32;
        int t = tid;
        if (t < 256) {
            float cmp[NBq];
            if (rs < Rq)
#pragma unroll
                for (int nb = 0; nb < NBq; ++nb) cmp[nb] = comp[rs * NBq + nb];
            for (int dl = 0; dl < 32; ++dl) {
                int d = d0 + dl;
                float val;
                if (rs < Rq) {
                    val = 0.f;
#pragma unroll
                    for (int nb = 0; nb < NBq; ++nb)
                        val += cmp[nb] * bases[((size_t)nb * Dq + d) * Hq + t];
                } else {
                    val = rootw[(size_t)d * Hq + t];
                }
                Ld[dl * 257 + t] = val;
            }
        }
        __syncthreads();
        if (t < 256) {
            int c = t & 31, hg = t >> 5;
            for (int hh = 0; hh < 32; ++hh) {
                int h = hg * 32 + hh;
                Wt[(size_t)(rs * 256 + h) * Dq + d0 + c] = f2bf(Ld[c * 257 + h]);
            }
        }
    } else {
        // ---- pre-stage Xs for this block's phase-2 graph (persists across grid sync) ----
        stageXs();
    }

    __threadfence();                  // device-scope release: flush A2b/Wt out of this XCD's L2
    cg::this_grid().sync();

    // =============================== PHASE 2: gemm3 ===============================
    if (blk < 112) stageXs();         // blocks that used LDS for attn/Wt restage Xs

    const int wrz = w >> 1, wcz = w & 1;   // gemm-Z grid: 4(h) x 2(s), waves 0..7
    const int wrn = w >> 2, wcn = w & 3;   // out grid: 2(nl) x 4(h), waves 0..7

    auto stageW = [&](char* Wbuf, int slice) {
        int kkbase = slice * 256 + hc * 64;
#pragma unroll
        for (int i = 0; i < 4; ++i) {
            int idx = i * 576 + tid;
            if (idx < 2048) {                 // boundary at i=3,w=5,l=0: wave-aligned
                int hrow = idx >> 5, c = idx & 31;
                const unsigned short* g = Wt + (size_t)(kkbase + hrow) * Dq + (c ^ (hrow & 7)) * 8;
                __builtin_amdgcn_global_load_lds((gu32*)g,
                    (lu32*)(unsigned int)(uintptr_t)(Wbuf + idx * 16), 16, 0, 0);
            }
        }
    };
    auto stageA2 = [&](int r) {               // 1152 chunks = 2x576 exact
#pragma unroll
        for (int i = 0; i < 2; ++i) {
            int idx = i * 576 + tid;
            int row = idx / 12, u = idx - row * 12;
            int usw = u ^ (row & 3);
            const unsigned short* g = A2b + ((size_t)b * 96 + row) * KAq + r * 96 + usw * 8;
            __builtin_amdgcn_global_load_lds((gu32*)g,
                (lu32*)(unsigned int)(uintptr_t)(A2l + idx * 16), 16, 0, 0);
        }
    };
    auto gemmZ = [&](char* Wbuf, f32x4 (&zacc)[3]) {
#pragma unroll
        for (int i = 0; i < 3; ++i) zacc[i] = (f32x4)0.0f;
#pragma unroll
        for (int ks = 0; ks < 8; ++ks) {
            int kb = ks * 64 + (l >> 4) * 16;
            int hl = wrz * 16 + (l & 15);
            bf16x8 af = *(const bf16x8*)(Wbuf + hl * 512 + (kb ^ ((hl & 7) << 4)));
#pragma unroll
            for (int ni = 0; ni < 3; ++ni) {
                int s = wcz * 48 + ni * 16 + (l & 15);
                bf16x8 xv = *(const bf16x8*)(Xs + s * 512 + (kb ^ ((s & 7) << 4)));
                zacc[ni] = __builtin_amdgcn_mfma_f32_16x16x32_bf16(af, xv, zacc[ni], 0, 0, 0);
            }
        }
    };
    auto writeZt = [&](f32x4 (&zacc)[3]) {
#pragma unroll
        for (int ni = 0; ni < 3; ++ni)
#pragma unroll
            for (int j = 0; j < 4; ++j) {
                int h = wrz * 16 + (l >> 4) * 4 + j;
                int s = wcz * 48 + ni * 16 + (l & 15);
                *(unsigned short*)(Ztl + h * 192 + (((s >> 3) ^ (h & 3)) << 4) + (s & 7) * 2)
                    = f2bf(zacc[ni][j]);
            }
    };

    stageW(Wl0, 0);
    stageA2(0);
    __syncthreads();                      // Xs + Wl0 + A2l(0) ready

    f32x4 acc[3];
#pragma unroll
    for (int i = 0; i < 3; ++i) acc[i] = (f32x4)0.0f;

    char* Wcur = Wl0;
    char* Wnxt = Wl1;
    for (int r = 0; r < Rq; ++r) {
        f32x4 zacc[3];
        if (w < 8) gemmZ(Wcur, zacc);
        stageW(Wnxt, r + 1);              // prefetch next slice (r=4 -> root slice 5)
        if (w < 8) writeZt(zacc);
        __syncthreads();                  // Ztl visible; Wnxt + A2l glds drained
#pragma unroll
        for (int ks = 0; ks < 3; ++ks) {
            if (w < 8) {
                int kb = ks * 64 + (l >> 4) * 16;
                int h = wcn * 16 + (l & 15);
                bf16x8 bfv = *(const bf16x8*)(Ztl + h * 192 + (kb ^ ((h & 3) << 4)));
#pragma unroll
                for (int mi = 0; mi < 3; ++mi) {
                    int nl = wrn * 48 + mi * 16 + (l & 15);
                    bf16x8 af = *(const bf16x8*)(A2l + nl * 192 + (kb ^ ((nl & 3) << 4)));
                    acc[mi] = __builtin_amdgcn_mfma_f32_16x16x32_bf16(af, bfv, acc[mi], 0, 0, 0);
                }
            }
        }
        __syncthreads();                  // out-MFMA done reading A2l & Ztl
        if (r < Rq - 1) stageA2(r + 1);   // refill A2l (drained at next iter's sync)
        char* t2 = Wcur; Wcur = Wnxt; Wnxt = t2;
    }

    // root term: Z5 = root-chunk @ X^T (staged in Wcur), add elementwise + bias, store
    f32x4 zacc[3];
    if (w < 8) gemmZ(Wcur, zacc);
    if (w < 8) writeZt(zacc);
    __syncthreads();
    if (w < 8) {
        int h = wcn * 16 + (l & 15);
        float bv = bias[hc * 64 + h];
#pragma unroll
        for (int mi = 0; mi < 3; ++mi) {
#pragma unroll
            for (int j = 0; j < 4; ++j) {
                int nl = wrn * 48 + mi * 16 + (l >> 4) * 4 + j;
                float rv = bf2f(*(const unsigned short*)(Ztl + h * 192 +
                                (((nl >> 3) ^ (h & 3)) << 4) + (nl & 7) * 2));
                if (nl < NPGq)
                    out[((size_t)b * NPGq + nl) * Hq + hc * 64 + h] = acc[mi][j] + rv + bv;
            }
        }
    }
}

extern "C" void kernel_launch(void* const* d_in, const int* in_sizes, int n_in,
                              void* d_out, int out_size, void* d_ws, size_t ws_size,
                              hipStream_t stream) {
    (void)in_sizes; (void)n_in; (void)out_size; (void)ws_size;
    const float* M     = (const float*)d_in[0];
    const float* x     = (const float*)d_in[1];
    const float* natt  = (const float*)d_in[2];
    const float* Ws    = (const float*)d_in[3];
    const float* bases = (const float*)d_in[4];
    const float* comp  = (const float*)d_in[5];
    const float* rootw = (const float*)d_in[6];
    const float* bias  = (const float*)d_in[7];
    const int* esrc    = (const int*)d_in[8];
    const int* edst    = (const int*)d_in[9];
    const int* etype   = (const int*)d_in[10];
    float* out = (float*)d_out;
    char* ws = (char*)d_ws;

    unsigned short* Wt  = (unsigned short*)(ws + 0);          //   786,432 B
    unsigned short* A2b = (unsigned short*)(ws + 786432);     // 5,898,240 B (total ~6.7 MB)

    void* args[] = {(void*)&M, (void*)&Ws, (void*)&natt, (void*)&esrc, (void*)&edst,
                    (void*)&etype, (void*)&x, (void*)&bases, (void*)&comp, (void*)&rootw,
                    (void*)&bias, (void*)&A2b, (void*)&Wt, (void*)&out};
    hipLaunchCooperativeKernel((const void*)k_all, dim3(256), dim3(576), args, 0, stream);
}

// Round 18
// 41.227 us; speedup vs baseline: 3.1051x; 3.1051x over previous
//
#include <hip/hip_runtime.h>
#include <cstddef>
#include <cstdint>

#define Bq 64
#define Tq 90
#define Oq 5
#define Dq 256
#define Hq 256
#define EAq 4096
#define Rq 5
#define NBq 8
#define NPGq 95
#define Nq 6080           // B*NPG real nodes
#define NPq 6144          // padded node space: 64 graphs x 96
#define EPBq 4546         // EA + T*O
#define Eq 290944         // B*EPB
#define KAq 480           // A2 cols: 5 relations x 96

typedef __attribute__((ext_vector_type(8))) short bf16x8;
typedef __attribute__((ext_vector_type(8))) unsigned short u16x8;
typedef __attribute__((ext_vector_type(4))) float f32x4;
typedef __attribute__((address_space(1))) const unsigned int gu32;
typedef __attribute__((address_space(3))) unsigned int lu32;

__device__ __forceinline__ unsigned short f2bf(float f) {
    unsigned u = __float_as_uint(f);
    unsigned r = (u + 0x7FFF + ((u >> 16) & 1)) >> 16;
    return (unsigned short)r;
}
__device__ __forceinline__ float bf2f(unsigned short s) {
    return __uint_as_float(((unsigned)s) << 16);
}

// ---------------- L1: blocks 0..63 attn -> A2b; 64..405 x->xb; 406..453 Wt
__global__ __launch_bounds__(576) void k_pa(const float* __restrict__ M,
                                            const float* __restrict__ Ws,
                                            const float* __restrict__ natt,
                                            const int* __restrict__ esrc,
                                            const int* __restrict__ edst,
                                            const int* __restrict__ etype,
                                            const float* __restrict__ x,
                                            const float* __restrict__ bases,
                                            const float* __restrict__ comp,
                                            const float* __restrict__ rootw,
                                            unsigned short* __restrict__ A2b,
                                            unsigned short* __restrict__ xb,
                                            unsigned short* __restrict__ Wt) {
    __shared__ __attribute__((aligned(16))) char lds[99072];
    const int tid = threadIdx.x;
    const int w = tid >> 6, l = tid & 63;
    const int blk = blockIdx.x;

    if (blk >= 64 && blk < 406) {
        // ---- xb conversion (x fp32 -> padded bf16 rows) ----
        unsigned i = (unsigned)(blk - 64) * 576 + tid;
        if (i < NPq * 32) {
            unsigned np = i >> 5, c = i & 31;
            unsigned s = np % 96;
            u16x8 pk;
            if (s == 95) {
#pragma unroll
                for (int q = 0; q < 8; ++q) pk[q] = 0;
            } else {
                unsigned node = np - np / 96;
                const float4* xs = (const float4*)(x + (size_t)node * Dq + c * 8);
                float4 a = xs[0], b2 = xs[1];
                pk[0] = f2bf(a.x);  pk[1] = f2bf(a.y);  pk[2] = f2bf(a.z);  pk[3] = f2bf(a.w);
                pk[4] = f2bf(b2.x); pk[5] = f2bf(b2.y); pk[6] = f2bf(b2.z); pk[7] = f2bf(b2.w);
            }
            *(u16x8*)(xb + (size_t)np * Dq + c * 8) = pk;
        }
        return;
    }
    if (blk >= 406) {
        // ---- Wt compute (256 active threads; barrier hoisted to all-thread level) ----
        float* Ld = (float*)lds;          // [32][257]
        int wblk = blk - 406;             // 0..47
        int rs = wblk >> 3;               // 0..5
        int d0 = (wblk & 7) * 32;
        int t = tid;
        if (t < 256) {
            float cmp[NBq];
            if (rs < Rq)
#pragma unroll
                for (int nb = 0; nb < NBq; ++nb) cmp[nb] = comp[rs * NBq + nb];
            for (int dl = 0; dl < 32; ++dl) {
                int d = d0 + dl;
                float v;
                if (rs < Rq) {
                    v = 0.f;
#pragma unroll
                    for (int nb = 0; nb < NBq; ++nb)
                        v += cmp[nb] * bases[((size_t)nb * Dq + d) * Hq + t];
                } else {
                    v = rootw[(size_t)d * Hq + t];
                }
                Ld[dl * 257 + t] = v;
            }
        }
        __syncthreads();
        if (t < 256) {
            int c = t & 31, hg = t >> 5;
            for (int hh = 0; hh < 32; ++hh) {
                int h = hg * 32 + hh;
                Wt[(size_t)(rs * 256 + h) * Dq + d0 + c] = f2bf(Ld[c * 257 + h]);
            }
        }
        return;
    }

    // ======================= ATTN PATH (R13-proven LDS-scatter) ======================
    unsigned short* Mb = (unsigned short*)lds;           // [96][256] bf16 swz (48KB)
    unsigned short* Wb = (unsigned short*)(lds + 49152); // [96][256] bf16 swz (48KB)
    float* P   = (float*)lds;                            // [96][97] fp32 (reuses Mb)
    float* Acc = (float*)(lds + 49152);                  // [96][96] fp32 (reuses Wb)
    float* mxs = (float*)(lds + 98304);                  // [96]
    float* rds = (float*)(lds + 98688);                  // [96]
    const int b = blk;

    int es[8], ed[8], et[8];
#pragma unroll
    for (int k = 0; k < 8; ++k) {
        int j = tid + k * 576;
        if (j < EAq) {
            es[k] = esrc[(size_t)b * EAq + j];
            ed[k] = edst[(size_t)b * EAq + j];
            et[k] = etype[(size_t)b * EAq + j];
        }
    }
    float tagv = (tid < Tq * Oq) ? natt[(size_t)b * (Tq * Oq) + tid] : 0.f;

#pragma unroll
    for (int i = 0; i < 6; ++i) {
        int idx = tid + i * 576;            // 0..3455, want 0..3071
        if (idx < 3072) {
            int row = idx >> 5, c = idx & 31;
            u16x8 pm, pw;
            if (row < Tq) {
                const float4* ms = (const float4*)(M + ((size_t)b * Tq + row) * Dq + c * 8);
                float4 a0 = ms[0], a1 = ms[1];
                pm[0] = f2bf(a0.x); pm[1] = f2bf(a0.y); pm[2] = f2bf(a0.z); pm[3] = f2bf(a0.w);
                pm[4] = f2bf(a1.x); pm[5] = f2bf(a1.y); pm[6] = f2bf(a1.z); pm[7] = f2bf(a1.w);
                const float4* ws = (const float4*)(Ws + (size_t)row * Dq + c * 8);
                float4 w0 = ws[0], w1 = ws[1];
                pw[0] = f2bf(w0.x); pw[1] = f2bf(w0.y); pw[2] = f2bf(w0.z); pw[3] = f2bf(w0.w);
                pw[4] = f2bf(w1.x); pw[5] = f2bf(w1.y); pw[6] = f2bf(w1.z); pw[7] = f2bf(w1.w);
            } else {
#pragma unroll
                for (int q = 0; q < 8; ++q) { pm[q] = 0; pw[q] = 0; }
            }
            int off = row * 512 + ((c * 16) ^ ((row & 7) << 4));
            *(u16x8*)((char*)Mb + off) = pm;
            *(u16x8*)((char*)Wb + off) = pw;
        }
    }
    __syncthreads();

    const int wr = w / 3, wc = w % 3;
    f32x4 acc[2][2];
#pragma unroll
    for (int i = 0; i < 2; ++i)
#pragma unroll
        for (int j = 0; j < 2; ++j) acc[i][j] = (f32x4)0.0f;
#pragma unroll
    for (int ks = 0; ks < 8; ++ks) {
        int kb = ks * 64 + (l >> 4) * 16;
        bf16x8 af[2], bfv[2];
#pragma unroll
        for (int mi = 0; mi < 2; ++mi) {
            int row = wr * 32 + mi * 16 + (l & 15);
            af[mi] = *(const bf16x8*)((char*)Mb + row * 512 + (kb ^ ((row & 7) << 4)));
        }
#pragma unroll
        for (int ni = 0; ni < 2; ++ni) {
            int row = wc * 32 + ni * 16 + (l & 15);
            bfv[ni] = *(const bf16x8*)((char*)Wb + row * 512 + (kb ^ ((row & 7) << 4)));
        }
#pragma unroll
        for (int mi = 0; mi < 2; ++mi)
#pragma unroll
            for (int ni = 0; ni < 2; ++ni)
                acc[mi][ni] = __builtin_amdgcn_mfma_f32_16x16x32_bf16(
                    af[mi], bfv[ni], acc[mi][ni], 0, 0, 0);
    }
    __syncthreads();   // MFMA reads done; Mb->P, Wb->Acc reuse now legal

#pragma unroll
    for (int mi = 0; mi < 2; ++mi)
#pragma unroll
        for (int ni = 0; ni < 2; ++ni)
#pragma unroll
            for (int j = 0; j < 4; ++j) {
                int rowp = wr * 32 + mi * 16 + (l >> 4) * 4 + j;
                int colp = wc * 32 + ni * 16 + (l & 15);
                P[rowp * 97 + colp] = acc[mi][ni][j];
            }
    __syncthreads();

    if (tid < 96) {
        float m = -1e30f;
        for (int t = 0; t < Tq; ++t) m = fmaxf(m, P[t * 97 + tid]);
        float s = 0.f;
        for (int t = 0; t < Tq; ++t) s += __expf(P[t * 97 + tid] - m);
        mxs[tid] = m;
        rds[tid] = 1.f / s;
    }
    __syncthreads();

    float v[8];
#pragma unroll
    for (int k = 0; k < 8; ++k) {
        int j = tid + k * 576;
        if (j < EAq)
            v[k] = __expf(P[ed[k] * 97 + es[k]] - mxs[es[k]]) * rds[es[k]];
    }

    for (int r = 0; r < Rq; ++r) {
#pragma unroll
        for (int i = 0; i < 4; ++i)
            ((float4*)Acc)[tid + i * 576] = make_float4(0.f, 0.f, 0.f, 0.f);
        __syncthreads();
#pragma unroll
        for (int k = 0; k < 8; ++k) {
            int j = tid + k * 576;
            if (j < EAq && et[k] == r)
                atomicAdd(&Acc[ed[k] * 96 + es[k]], v[k]);
        }
        if (r == Rq - 1 && tid < Tq * Oq) {
            int t = tid / Oq, o = tid % Oq;
            Acc[(Tq + o) * 96 + t] = tagv;
        }
        __syncthreads();
#pragma unroll
        for (int i = 0; i < 2; ++i) {
            int c0 = tid + i * 576;                      // 0..1151
            const float* src = Acc + (c0 / 12) * 96 + (c0 % 12) * 8;
            u16x8 pk;
#pragma unroll
            for (int q = 0; q < 8; ++q) pk[q] = f2bf(src[q]);
            *(u16x8*)(A2b + ((size_t)b * 96 + c0 / 12) * KAq + r * 96 + (c0 % 12) * 8) = pk;
        }
        __syncthreads();
    }
}

// ---------------- L2: fused per-graph back-half (R11-proven + dbuf W + bf16 A2 glds)
// block (hc, b): acc[96 nl][64 h] = sum_r A2_r @ (W_r-chunk @ X_b^T)^T + root + bias
__global__ __launch_bounds__(512) void k_gemm3(const unsigned short* __restrict__ A2b,
                                               const unsigned short* __restrict__ Wt,
                                               const unsigned short* __restrict__ xb,
                                               const float* __restrict__ bias,
                                               float* __restrict__ out) {
    __shared__ __attribute__((aligned(16))) char lds[145408];
    char* const Xs  = lds;               // [96][512B]  swizzled bf16   48KB
    char* const Wl0 = lds + 49152;       // [64][512B]  swizzled bf16   32KB
    char* const Wl1 = lds + 81920;       // [64][512B]  swizzled bf16   32KB
    char* const Ztl = lds + 114688;      // [64][192B]  swizzled bf16   12KB
    char* const A2l = lds + 126976;      // [96][192B]  swizzled bf16   18KB
    const int hc = blockIdx.x;           // 0..3
    const int b  = blockIdx.y;           // 0..63
    const int tid = threadIdx.x;
    const int w = tid >> 6, l = tid & 63;
    const int wrz = w >> 1, wcz = w & 1;   // gemm-Z grid: 4(h) x 2(s)
    const int wrn = w >> 2, wcn = w & 3;   // gemm-out grid: 2(nl) x 4(h)

    // stage X_b once (3072 chunks, 6 iters)
#pragma unroll
    for (int i = 0; i < 6; ++i) {
        int idx = i * 512 + tid;
        int row = idx >> 5, c = idx & 31;
        const unsigned short* g = xb + (size_t)(b * 96 + row) * Dq + (c ^ (row & 7)) * 8;
        __builtin_amdgcn_global_load_lds((gu32*)g,
            (lu32*)(unsigned int)(uintptr_t)(Xs + idx * 16), 16, 0, 0);
    }

    f32x4 acc[3];
#pragma unroll
    for (int i = 0; i < 3; ++i) acc[i] = (f32x4)0.0f;

    auto stageW = [&](char* Wbuf, int slice) {
        int kkbase = slice * 256 + hc * 64;      // slice 0..4 relations, 5 = root
#pragma unroll
        for (int i = 0; i < 4; ++i) {
            int idx = i * 512 + tid;
            int hrow = idx >> 5, c = idx & 31;
            const unsigned short* g = Wt + (size_t)(kkbase + hrow) * Dq + (c ^ (hrow & 7)) * 8;
            __builtin_amdgcn_global_load_lds((gu32*)g,
                (lu32*)(unsigned int)(uintptr_t)(Wbuf + idx * 16), 16, 0, 0);
        }
    };
    auto stageA2 = [&](int r) {                  // 1152 chunks, pre-swizzled source
#pragma unroll
        for (int i = 0; i < 3; ++i) {
            int idx = i * 512 + tid;
            if (idx < 1152) {
                int row = idx / 12, u = idx - row * 12;
                int usw = u ^ (row & 3);
                const unsigned short* g = A2b + ((size_t)b * 96 + row) * KAq + r * 96 + usw * 8;
                __builtin_amdgcn_global_load_lds((gu32*)g,
                    (lu32*)(unsigned int)(uintptr_t)(A2l + idx * 16), 16, 0, 0);
            }
        }
    };
    auto gemmZ = [&](char* Wbuf, f32x4 (&zacc)[3]) {   // zacc[ni] over (16h x 48s)
#pragma unroll
        for (int i = 0; i < 3; ++i) zacc[i] = (f32x4)0.0f;
#pragma unroll
        for (int ks = 0; ks < 8; ++ks) {
            int kb = ks * 64 + (l >> 4) * 16;
            int hl = wrz * 16 + (l & 15);
            bf16x8 af = *(const bf16x8*)(Wbuf + hl * 512 + (kb ^ ((hl & 7) << 4)));
#pragma unroll
            for (int ni = 0; ni < 3; ++ni) {
                int s = wcz * 48 + ni * 16 + (l & 15);
                bf16x8 xv = *(const bf16x8*)(Xs + s * 512 + (kb ^ ((s & 7) << 4)));
                zacc[ni] = __builtin_amdgcn_mfma_f32_16x16x32_bf16(af, xv, zacc[ni], 0, 0, 0);
            }
        }
    };
    auto writeZt = [&](f32x4 (&zacc)[3]) {
#pragma unroll
        for (int ni = 0; ni < 3; ++ni)
#pragma unroll
            for (int j = 0; j < 4; ++j) {
                int h = wrz * 16 + (l >> 4) * 4 + j;
                int s = wcz * 48 + ni * 16 + (l & 15);
                *(unsigned short*)(Ztl + h * 192 + (((s >> 3) ^ (h & 3)) << 4) + (s & 7) * 2)
                    = f2bf(zacc[ni][j]);
            }
    };

    stageW(Wl0, 0);
    stageA2(0);
    __syncthreads();                      // Xs, Wl0, A2l(r=0) ready

    char* Wcur = Wl0;
    char* Wnxt = Wl1;
    for (int r = 0; r < Rq; ++r) {
        f32x4 zacc[3];
        gemmZ(Wcur, zacc);                // reads Wcur, Xs
        stageW(Wnxt, r + 1);              // prefetch next slice (r=4 -> root slice 5)
        writeZt(zacc);                    // Ztl free (prev consumer done at last sync)
        __syncthreads();                  // Ztl visible; A2l loads drained
        // acc[nl][h] += A2_r @ Zt^T : K = 96 s
#pragma unroll
        for (int ks = 0; ks < 3; ++ks) {
            int kb = ks * 64 + (l >> 4) * 16;
            int h = wcn * 16 + (l & 15);
            bf16x8 bfv = *(const bf16x8*)(Ztl + h * 192 + (kb ^ ((h & 3) << 4)));
#pragma unroll
            for (int mi = 0; mi < 3; ++mi) {
                int nl = wrn * 48 + mi * 16 + (l & 15);
                bf16x8 af = *(const bf16x8*)(A2l + nl * 192 + (kb ^ ((nl & 3) << 4)));
                acc[mi] = __builtin_amdgcn_mfma_f32_16x16x32_bf16(af, bfv, acc[mi], 0, 0, 0);
            }
        }
        __syncthreads();                  // out-MFMA done reading A2l & Ztl
        if (r < Rq - 1) stageA2(r + 1);   // refill A2l for next relation
        char* t2 = Wcur; Wcur = Wnxt; Wnxt = t2;
    }

    // root term: Z5 = root-chunk @ X^T (already staged in Wcur), add elementwise
    f32x4 zacc[3];
    gemmZ(Wcur, zacc);
    writeZt(zacc);
    __syncthreads();
#pragma unroll
    for (int mi = 0; mi < 3; ++mi) {
        int h = wcn * 16 + (l & 15);
#pragma unroll
        for (int j = 0; j < 4; ++j) {
            int nl = wrn * 48 + mi * 16 + (l >> 4) * 4 + j;
            float rv = bf2f(*(const unsigned short*)(Ztl + h * 192 +
                            (((nl >> 3) ^ (h & 3)) << 4) + (nl & 7) * 2));
            acc[mi][j] += rv;
        }
    }

    {
        int h = wcn * 16 + (l & 15);
        float bv = bias[hc * 64 + h];
#pragma unroll
        for (int mi = 0; mi < 3; ++mi)
#pragma unroll
            for (int j = 0; j < 4; ++j) {
                int nl = wrn * 48 + mi * 16 + (l >> 4) * 4 + j;
                if (nl < NPGq)
                    out[((size_t)b * NPGq + nl) * Hq + hc * 64 + h] = acc[mi][j] + bv;
            }
    }
}

extern "C" void kernel_launch(void* const* d_in, const int* in_sizes, int n_in,
                              void* d_out, int out_size, void* d_ws, size_t ws_size,
                              hipStream_t stream) {
    (void)in_sizes; (void)n_in; (void)out_size; (void)ws_size;
    const float* M     = (const float*)d_in[0];
    const float* x     = (const float*)d_in[1];
    const float* natt  = (const float*)d_in[2];
    const float* Ws    = (const float*)d_in[3];
    const float* bases = (const float*)d_in[4];
    const float* comp  = (const float*)d_in[5];
    const float* rootw = (const float*)d_in[6];
    const float* bias  = (const float*)d_in[7];
    const int* esrc    = (const int*)d_in[8];
    const int* edst    = (const int*)d_in[9];
    const int* etype   = (const int*)d_in[10];
    float* out = (float*)d_out;
    char* ws = (char*)d_ws;

    unsigned short* Wt  = (unsigned short*)(ws + 0);          //    786,432 B
    unsigned short* A2b = (unsigned short*)(ws + 786432);     //  5,898,240 B
    unsigned short* xb  = (unsigned short*)(ws + 6684672);    //  3,145,728 B (total ~9.8 MB)

    k_pa<<<dim3(454), 576, 0, stream>>>(M, Ws, natt, esrc, edst, etype,
                                        x, bases, comp, rootw, A2b, xb, Wt);
    k_gemm3<<<dim3(4, Bq), 512, 0, stream>>>(A2b, Wt, xb, bias, out);
}